// Round 1
// baseline (14727.142 us; speedup 1.0000x reference)
//
#include <hip/hip_runtime.h>

#define B_ 8
#define R_ 128
#define T_ 64
#define FIN_ 32
#define L_ 64
#define D_ 64
#define H_ 128
#define OUT_ 32
#define ES_ 2048

__device__ __forceinline__ float silu_f(float x) { return x / (1.f + __expf(-x)); }
__device__ __forceinline__ float tanh_f(float x) {
    float e = __expf(2.f * x);
    return 1.f - 2.f / (e + 1.f);
}

// ---------------------------------------------------------------------------
// prep: deterministic CSR build (edges sorted by dst, stable order) + permuted
// per-batch edge weights. One block, 128 threads (thread r owns dst row r).
// ---------------------------------------------------------------------------
__global__ __launch_bounds__(128) void prep_kernel(
    const int* __restrict__ src, const int* __restrict__ dst,
    const float* __restrict__ space_w,
    int* __restrict__ row_start, int* __restrict__ esrcp, float* __restrict__ wperm) {
    __shared__ int cnt[R_];
    __shared__ int rs[R_ + 1];
    __shared__ int permS[ES_];
    int r = threadIdx.x;
    int c = 0;
    for (int e = 0; e < ES_; ++e) c += (dst[e] == r) ? 1 : 0;
    cnt[r] = c;
    __syncthreads();
    if (r == 0) {
        int a = 0;
        for (int i = 0; i < R_; ++i) { rs[i] = a; a += cnt[i]; }
        rs[R_] = a;
    }
    __syncthreads();
    {
        int k = rs[r];
        for (int e = 0; e < ES_; ++e)
            if (dst[e] == r) permS[k++] = e;
    }
    __syncthreads();
    row_start[r] = rs[r];
    if (r == 0) row_start[R_] = rs[R_];
    for (int e = r; e < ES_; e += 128) esrcp[e] = src[permS[e]];
    for (int i = r; i < B_ * ES_; i += 128) {
        int b = i >> 11;
        int e = i & (ES_ - 1);
        wperm[i] = space_w[b * ES_ + permS[e]];
    }
}

// ---------------------------------------------------------------------------
// encoder: one block per (b,r). h1 = silu(x@We1+b1), h2 = silu(h1@We2+b2),
// hp = mean_t h2, then mu/sigma/v -> Lz, Dz, dyn = Dz@Wdyn.
// ---------------------------------------------------------------------------
__global__ __launch_bounds__(256) void encoder_kernel(
    const float* __restrict__ node_feats, const float* __restrict__ eps,
    const float* __restrict__ W_e1, const float* __restrict__ b_e1,
    const float* __restrict__ W_e2, const float* __restrict__ b_e2,
    const float* __restrict__ W_mu, const float* __restrict__ W_sig,
    const float* __restrict__ W_dyn,
    float* __restrict__ Lz, float* __restrict__ Dz, float* __restrict__ dynb) {
    int br = blockIdx.x;
    int tid = threadIdx.x;
    __shared__ float xS[T_ * 33];                       // 8.4 KB
    __shared__ float we1[33 * H_];                      // 16.9 KB
    __shared__ __align__(16) float h1[T_ * H_];         // 32 KB
    __shared__ float hps[2 * H_];
    __shared__ float hp[H_];
    __shared__ float muS[H_], sgS[H_], vS[H_];

    const float* nf = node_feats + (size_t)br * (T_ * FIN_);
    for (int i = tid; i < T_ * FIN_; i += 256) {
        int t = i >> 5, f = i & 31;
        xS[t * 33 + f] = nf[i];
    }
    if (tid < T_) xS[tid * 33 + 32] = (float)tid * (1.f / 64.f);
    for (int i = tid; i < 33 * H_; i += 256) we1[i] = W_e1[i];
    __syncthreads();

    int j = tid & 127;
    int th = tid >> 7;
    float be1 = b_e1[j];
    for (int tt = 0; tt < 32; ++tt) {
        int t = th * 32 + tt;
        float a = be1;
        #pragma unroll
        for (int k = 0; k < 33; ++k) a += xS[t * 33 + k] * we1[k * H_ + j];
        h1[t * H_ + j] = silu_f(a);
    }
    __syncthreads();

    float acc[32];
    float be2 = b_e2[j];
    #pragma unroll
    for (int tt = 0; tt < 32; ++tt) acc[tt] = be2;
    for (int kc = 0; kc < 4; ++kc) {
        float wreg[32];
        #pragma unroll
        for (int i2 = 0; i2 < 32; ++i2) wreg[i2] = W_e2[(kc * 32 + i2) * H_ + j];
        #pragma unroll
        for (int tt = 0; tt < 32; ++tt) {
            int t = th * 32 + tt;
            const float4* hrow = (const float4*)(&h1[t * H_ + kc * 32]);
            float s = 0.f;
            #pragma unroll
            for (int w4 = 0; w4 < 8; ++w4) {
                float4 hv = hrow[w4];
                s += hv.x * wreg[w4 * 4 + 0] + hv.y * wreg[w4 * 4 + 1] +
                     hv.z * wreg[w4 * 4 + 2] + hv.w * wreg[w4 * 4 + 3];
            }
            acc[tt] += s;
        }
    }
    float msum = 0.f;
    #pragma unroll
    for (int tt = 0; tt < 32; ++tt) msum += silu_f(acc[tt]);
    hps[th * H_ + j] = msum;
    __syncthreads();
    if (tid < H_) hp[tid] = (hps[tid] + hps[H_ + tid]) * (1.f / 64.f);
    __syncthreads();

    {
        const float* Wm = (th == 0) ? W_mu : W_sig;
        float a = 0.f;
        #pragma unroll 4
        for (int k = 0; k < H_; ++k) a += hp[k] * Wm[k * H_ + j];
        if (th == 0) muS[j] = a; else sgS[j] = a;
    }
    __syncthreads();
    if (tid < H_) {
        float sig = 0.1f + 0.9f / (1.f + __expf(-sgS[tid]));
        float v = muS[tid] + sig * eps[(size_t)br * H_ + tid];
        vS[tid] = v;
        if (tid < L_) Lz[(size_t)br * L_ + tid] = v;
        else          Dz[(size_t)br * D_ + (tid - L_)] = v;
    }
    __syncthreads();
    if (tid < L_) {
        float a = 0.f;
        #pragma unroll 4
        for (int k = 0; k < D_; ++k) a += vS[L_ + k] * W_dyn[k * L_ + tid];
        dynb[(size_t)br * L_ + tid] = a;
    }
}

// ---------------------------------------------------------------------------
// ode: one block per batch (8 blocks x 1024 threads). 64 RK4 steps fully in
// LDS. thread (r = tid>>3, g = tid&7) owns state slots [r][g*8 .. g*8+8).
// xstage/aggl rows padded to 68 floats (conflict-free b128 across 8 rows/wave);
// transposed weights use XOR block swizzle kb ^= (j>>3) (8 rows at stride 8).
// 2 barriers per stage.
// ---------------------------------------------------------------------------
#define XPAD 68
__global__ __launch_bounds__(1024) void ode_kernel(
    const float* __restrict__ Lz, const float* __restrict__ dynb,
    const float* __restrict__ W_msg, const float* __restrict__ W_self,
    const float* __restrict__ b_ode,
    const int* __restrict__ row_start, const int* __restrict__ esrcp,
    const float* __restrict__ wperm,
    float* __restrict__ traj) {
    int b = blockIdx.x;
    int tid = threadIdx.x;
    int r = tid >> 3;
    int g = tid & 7;
    int f0 = g * 8;

    extern __shared__ float lds[];
    float* xstage = lds;                          // 128*68
    float* aggl   = xstage + 128 * XPAD;          // 128*68
    float* wmsgT  = aggl + 128 * XPAD;            // 64*64 (swizzled, [j][k])
    float* wselfT = wmsgT + 64 * 64;              // 64*64
    float* ewS    = wselfT + 64 * 64;             // 2048
    int*   esS    = (int*)(ewS + ES_);            // 2048
    int*   rsS    = esS + ES_;                    // 132

    for (int i = tid; i < L_ * L_; i += 1024) {   // i = k*64 + jj
        int k = i >> 6, jj = i & 63;
        int idx = jj * 64 + ((((k >> 2) ^ (jj >> 3)) & 15) << 2) + (k & 3);
        wmsgT[idx]  = W_msg[i];
        wselfT[idx] = W_self[i];
    }
    for (int i = tid; i < ES_; i += 1024) {
        ewS[i] = wperm[b * ES_ + i];
        esS[i] = esrcp[i];
    }
    if (tid < R_ + 1) rsS[tid] = row_start[tid];

    float xb[8], ks[8], dnb[8];
    {
        const float4* lp = (const float4*)(Lz + ((size_t)(b * R_ + r)) * L_ + f0);
        float4 l0 = lp[0], l1 = lp[1];
        xb[0] = l0.x; xb[1] = l0.y; xb[2] = l0.z; xb[3] = l0.w;
        xb[4] = l1.x; xb[5] = l1.y; xb[6] = l1.z; xb[7] = l1.w;
        const float4* dp = (const float4*)(dynb + ((size_t)(b * R_ + r)) * L_ + f0);
        float4 d0 = dp[0], d1 = dp[1];
        const float4* bp = (const float4*)(b_ode + f0);
        float4 o0 = bp[0], o1 = bp[1];
        dnb[0] = d0.x + o0.x; dnb[1] = d0.y + o0.y; dnb[2] = d0.z + o0.z; dnb[3] = d0.w + o0.w;
        dnb[4] = d1.x + o1.x; dnb[5] = d1.y + o1.y; dnb[6] = d1.z + o1.z; dnb[7] = d1.w + o1.w;
    }
    float* xrow_my = &xstage[r * XPAD + f0];
    ((float4*)xrow_my)[0] = make_float4(xb[0], xb[1], xb[2], xb[3]);
    ((float4*)xrow_my)[1] = make_float4(xb[4], xb[5], xb[6], xb[7]);
    __syncthreads();

    const int rs0 = rsS[r], rs1 = rsS[r + 1];

    for (int n = 0; n < T_; ++n) {
        #pragma unroll
        for (int i = 0; i < 8; ++i) ks[i] = 0.f;
        #pragma unroll
        for (int s = 0; s < 4; ++s) {
            const float wk = (s == 1 || s == 2) ? 2.f : 1.f;
            const float cn = (s < 2) ? 0.05f : 0.1f;
            // ---- gather: agg[r][f] = sum_e w_e * xstage[src_e][f]
            float agg[8];
            #pragma unroll
            for (int i = 0; i < 8; ++i) agg[i] = 0.f;
            for (int e = rs0; e < rs1; ++e) {
                float w = ewS[e];
                int sn = esS[e];
                const float4* xr4 = (const float4*)(xstage + sn * XPAD + f0);
                float4 a0 = xr4[0], a1 = xr4[1];
                agg[0] += w * a0.x; agg[1] += w * a0.y; agg[2] += w * a0.z; agg[3] += w * a0.w;
                agg[4] += w * a1.x; agg[5] += w * a1.y; agg[6] += w * a1.z; agg[7] += w * a1.w;
            }
            {
                float* ar = &aggl[r * XPAD + f0];
                ((float4*)ar)[0] = make_float4(agg[0], agg[1], agg[2], agg[3]);
                ((float4*)ar)[1] = make_float4(agg[4], agg[5], agg[6], agg[7]);
            }
            __syncthreads();  // all gathers done before anyone overwrites xstage

            // ---- k = tanh(agg@Wmsg + x@Wself + dyn + b)
            float acc0[8], acc1[8];
            #pragma unroll
            for (int i = 0; i < 8; ++i) { acc0[i] = 0.f; acc1[i] = 0.f; }
            {
                const float4* a4 = (const float4*)(&aggl[r * XPAD]);
                const float4* x4 = (const float4*)(&xstage[r * XPAD]);
                #pragma unroll
                for (int kb = 0; kb < 16; ++kb) {
                    float4 av = a4[kb];
                    float4 xv = x4[kb];
                    #pragma unroll
                    for (int i = 0; i < 8; ++i) {
                        int jj = f0 + i;
                        float4 wv = ((const float4*)&wmsgT[jj * 64])[kb ^ g];
                        float4 sv = ((const float4*)&wselfT[jj * 64])[kb ^ g];
                        acc0[i] += av.x * wv.x + av.y * wv.y + av.z * wv.z + av.w * wv.w;
                        acc1[i] += xv.x * sv.x + xv.y * sv.y + xv.z * sv.z + xv.w * sv.w;
                    }
                }
            }
            float kv[8];
            #pragma unroll
            for (int i = 0; i < 8; ++i) {
                kv[i] = tanh_f(acc0[i] + acc1[i] + dnb[i]);
                ks[i] += wk * kv[i];
            }
            if (s < 3) {
                ((float4*)xrow_my)[0] = make_float4(xb[0] + cn * kv[0], xb[1] + cn * kv[1],
                                                    xb[2] + cn * kv[2], xb[3] + cn * kv[3]);
                ((float4*)xrow_my)[1] = make_float4(xb[4] + cn * kv[4], xb[5] + cn * kv[5],
                                                    xb[6] + cn * kv[6], xb[7] + cn * kv[7]);
            } else {
                #pragma unroll
                for (int i = 0; i < 8; ++i) xb[i] += (0.1f / 6.f) * ks[i];
                ((float4*)xrow_my)[0] = make_float4(xb[0], xb[1], xb[2], xb[3]);
                ((float4*)xrow_my)[1] = make_float4(xb[4], xb[5], xb[6], xb[7]);
                float* tp = traj + (((size_t)b * T_ + n) * R_ + r) * L_ + f0;
                ((float4*)tp)[0] = make_float4(xb[0], xb[1], xb[2], xb[3]);
                ((float4*)tp)[1] = make_float4(xb[4], xb[5], xb[6], xb[7]);
            }
            __syncthreads();  // xstage updated before next stage's gather
        }
    }
}

// ---------------------------------------------------------------------------
// decoder: one block per (b,r). Exploits one-hot rid: base[j] = b_d1[j] +
// Dz@Wd1[64:128] + Wd1[129+r]. Per t: h = silu(base + t/64*wt + traj@Wd1[:64]),
// y = h@Wd2 + b_d2. Wd1[:64] column held in registers (64/thread).
// ---------------------------------------------------------------------------
__global__ __launch_bounds__(256) void decoder_kernel(
    const float* __restrict__ traj, const float* __restrict__ Dz,
    const float* __restrict__ W_d1, const float* __restrict__ b_d1,
    const float* __restrict__ W_d2, const float* __restrict__ b_d2,
    float* __restrict__ y) {
    int br = blockIdx.x;
    int b = br >> 7;
    int r = br & 127;
    int tid = threadIdx.x;
    __shared__ __align__(16) float trajS[32 * L_];  // 8 KB
    __shared__ __align__(16) float hS[32 * H_];     // 16 KB
    __shared__ float dzS[D_];
    __shared__ float baseS[H_];

    int j = tid & 127;
    int th = tid >> 7;
    if (tid < D_) dzS[tid] = Dz[(size_t)br * D_ + tid];
    __syncthreads();

    float wcol[64];
    #pragma unroll
    for (int k = 0; k < 64; ++k) wcol[k] = W_d1[k * H_ + j];
    float wt = W_d1[128 * H_ + j];
    if (th == 0) {
        float a = b_d1[j] + W_d1[(129 + r) * H_ + j];
        #pragma unroll 4
        for (int k = 0; k < D_; ++k) a += dzS[k] * W_d1[(64 + k) * H_ + j];
        baseS[j] = a;
    }
    __syncthreads();
    float bb = baseS[j];

    for (int half = 0; half < 2; ++half) {
        for (int i = tid; i < 32 * L_; i += 256) {
            int tt = i >> 6, l = i & 63;
            trajS[i] = traj[(((size_t)b * T_ + half * 32 + tt) * R_ + r) * L_ + l];
        }
        __syncthreads();
        #pragma unroll
        for (int tt = 0; tt < 16; ++tt) {
            int tl = th * 16 + tt;
            int t = half * 32 + tl;
            float a = bb + (float)t * (1.f / 64.f) * wt;
            const float4* tr4 = (const float4*)(&trajS[tl * L_]);
            #pragma unroll
            for (int kb = 0; kb < 16; ++kb) {
                float4 tv = tr4[kb];
                a += tv.x * wcol[kb * 4 + 0] + tv.y * wcol[kb * 4 + 1] +
                     tv.z * wcol[kb * 4 + 2] + tv.w * wcol[kb * 4 + 3];
            }
            hS[tl * H_ + j] = silu_f(a);
        }
        __syncthreads();
        {
            int o = tid & 31, q = tid >> 5;  // q = 0..7
            float acc2[4];
            float bd2 = b_d2[o];
            #pragma unroll
            for (int u = 0; u < 4; ++u) acc2[u] = bd2;
            for (int jc = 0; jc < 4; ++jc) {
                float wreg[32];
                #pragma unroll
                for (int i2 = 0; i2 < 32; ++i2) wreg[i2] = W_d2[(jc * 32 + i2) * OUT_ + o];
                #pragma unroll
                for (int u = 0; u < 4; ++u) {
                    int tl = q * 4 + u;
                    const float4* h4 = (const float4*)(&hS[tl * H_ + jc * 32]);
                    float s2 = 0.f;
                    #pragma unroll
                    for (int w4 = 0; w4 < 8; ++w4) {
                        float4 hv = h4[w4];
                        s2 += hv.x * wreg[w4 * 4 + 0] + hv.y * wreg[w4 * 4 + 1] +
                              hv.z * wreg[w4 * 4 + 2] + hv.w * wreg[w4 * 4 + 3];
                    }
                    acc2[u] += s2;
                }
            }
            #pragma unroll
            for (int u = 0; u < 4; ++u) {
                int t = half * 32 + q * 4 + u;
                y[((size_t)br * T_ + t) * OUT_ + o] = acc2[u];
            }
        }
        __syncthreads();
    }
}

extern "C" void kernel_launch(void* const* d_in, const int* in_sizes, int n_in,
                              void* d_out, int out_size, void* d_ws, size_t ws_size,
                              hipStream_t stream) {
    const float* node_feats = (const float*)d_in[0];
    const float* eps_       = (const float*)d_in[1];
    const float* space_w    = (const float*)d_in[2];
    const int*   src        = (const int*)d_in[3];
    const int*   dst        = (const int*)d_in[4];
    const float* W_e1 = (const float*)d_in[5];
    const float* b_e1 = (const float*)d_in[6];
    const float* W_e2 = (const float*)d_in[7];
    const float* b_e2 = (const float*)d_in[8];
    const float* W_mu = (const float*)d_in[9];
    const float* W_sig = (const float*)d_in[10];
    const float* W_msg = (const float*)d_in[11];
    const float* W_self = (const float*)d_in[12];
    const float* W_dyn = (const float*)d_in[13];
    const float* b_ode = (const float*)d_in[14];
    const float* W_d1 = (const float*)d_in[15];
    const float* b_d1 = (const float*)d_in[16];
    const float* W_d2 = (const float*)d_in[17];
    const float* b_d2 = (const float*)d_in[18];
    float* out = (float*)d_out;

    float* f_ws = (float*)d_ws;
    float* Lz    = f_ws;                          // 65536
    float* Dz    = Lz + B_ * R_ * L_;             // 65536
    float* dynb  = Dz + B_ * R_ * D_;             // 65536
    float* traj  = dynb + B_ * R_ * L_;           // 4194304
    float* wperm = traj + (size_t)B_ * T_ * R_ * L_;  // 16384
    int* row_start = (int*)(wperm + B_ * ES_);    // 132
    int* esrcp     = row_start + 132;             // 2048

    prep_kernel<<<1, 128, 0, stream>>>(src, dst, space_w, row_start, esrcp, wperm);
    encoder_kernel<<<B_ * R_, 256, 0, stream>>>(node_feats, eps_, W_e1, b_e1, W_e2, b_e2,
                                                W_mu, W_sig, W_dyn, Lz, Dz, dynb);
    size_t ode_lds = (size_t)(128 * XPAD * 2 + 64 * 64 * 2 + ES_) * sizeof(float) +
                     (size_t)(ES_ + 132) * sizeof(int);
    ode_kernel<<<B_, 1024, ode_lds, stream>>>(Lz, dynb, W_msg, W_self, b_ode,
                                              row_start, esrcp, wperm, traj);
    decoder_kernel<<<B_ * R_, 256, 0, stream>>>(traj, Dz, W_d1, b_d1, W_d2, b_d2, out);
}